// Round 17
// baseline (2060.250 us; speedup 1.0000x reference)
//
#include <hip/hip_runtime.h>
#include <math.h>

#define E_DIM 768
#define NTOK 1025
#define B_DIM 32
#define NHEADS 12
#define HDIM 64
#define LAYERS 12
#define FF_DIM 3072
#define P2 576

// ---------------- helpers ----------------
__device__ __forceinline__ float block_reduce_sum(float v, float* red) {
  int tid = threadIdx.x;
  red[tid] = v;
  __syncthreads();
#pragma unroll
  for (int s = 128; s > 0; s >>= 1) {
    if (tid < s) red[tid] += red[tid + s];
    __syncthreads();
  }
  float r = red[0];
  __syncthreads();
  return r;
}

// ---------------- embed GEMM: 128x128 tile, 8x8 acc, XCD-swizzled (r14) ----------------
__global__ __launch_bounds__(256) void embed_gemm(
    const float* __restrict__ A, const float* __restrict__ W,
    const float* __restrict__ bias, const float* __restrict__ pos,
    float* __restrict__ scene) {
  __shared__ float Xs[16][132];
  __shared__ float Ws[16][132];
  int tid = threadIdx.x;
  int bid = blockIdx.x;
  int xcd = bid & 7;
  int idx = bid >> 3;
  int m_tile = xcd * 32 + idx / 6;
  int n_tile = idx % 6;
  int n0 = n_tile * 128;
  int m0 = m_tile * 128;
  int lr = tid >> 2;
  int lk = (tid & 3) << 2;
  int ty = tid >> 4, tx = tid & 15;
  float acc[8][8] = {};
  for (int k0 = 0; k0 < P2; k0 += 16) {
    float4 x0 = *(const float4*)(A + (size_t)(m0 + lr) * P2 + k0 + lk);
    float4 x1 = *(const float4*)(A + (size_t)(m0 + 64 + lr) * P2 + k0 + lk);
    float4 w0 = *(const float4*)(W + (size_t)(n0 + lr) * P2 + k0 + lk);
    float4 w1 = *(const float4*)(W + (size_t)(n0 + 64 + lr) * P2 + k0 + lk);
    __syncthreads();
    Xs[lk + 0][lr] = x0.x; Xs[lk + 1][lr] = x0.y; Xs[lk + 2][lr] = x0.z; Xs[lk + 3][lr] = x0.w;
    Xs[lk + 0][64 + lr] = x1.x; Xs[lk + 1][64 + lr] = x1.y; Xs[lk + 2][64 + lr] = x1.z; Xs[lk + 3][64 + lr] = x1.w;
    Ws[lk + 0][lr] = w0.x; Ws[lk + 1][lr] = w0.y; Ws[lk + 2][lr] = w0.z; Ws[lk + 3][lr] = w0.w;
    Ws[lk + 0][64 + lr] = w1.x; Ws[lk + 1][64 + lr] = w1.y; Ws[lk + 2][64 + lr] = w1.z; Ws[lk + 3][64 + lr] = w1.w;
    __syncthreads();
#pragma unroll
    for (int kk = 0; kk < 16; ++kk) {
      float4 a0 = *(const float4*)&Xs[kk][ty << 2];
      float4 a1 = *(const float4*)&Xs[kk][64 + (ty << 2)];
      float4 b0 = *(const float4*)&Ws[kk][tx << 2];
      float4 b1 = *(const float4*)&Ws[kk][64 + (tx << 2)];
      float av[8] = {a0.x, a0.y, a0.z, a0.w, a1.x, a1.y, a1.z, a1.w};
      float bv[8] = {b0.x, b0.y, b0.z, b0.w, b1.x, b1.y, b1.z, b1.w};
#pragma unroll
      for (int i = 0; i < 8; ++i)
#pragma unroll
        for (int j = 0; j < 8; ++j) acc[i][j] += av[i] * bv[j];
    }
  }
#pragma unroll
  for (int i = 0; i < 8; ++i) {
    int mloc = (i < 4) ? ((ty << 2) + i) : (64 + (ty << 2) + i - 4);
    int m = m0 + mloc;
    int b = m >> 10, nt = m & 1023;
    size_t row = ((size_t)b * NTOK + 1 + nt) * E_DIM;
    size_t prow = (size_t)(1 + nt) * E_DIM;
#pragma unroll
    for (int half = 0; half < 2; ++half) {
      int n = n0 + half * 64 + (tx << 2);
      float4 o4;
      o4.x = acc[i][half * 4 + 0] + bias[n + 0] + pos[prow + n + 0];
      o4.y = acc[i][half * 4 + 1] + bias[n + 1] + pos[prow + n + 1];
      o4.z = acc[i][half * 4 + 2] + bias[n + 2] + pos[prow + n + 2];
      o4.w = acc[i][half * 4 + 3] + bias[n + 3] + pos[prow + n + 3];
      *(float4*)&scene[row + n] = o4;
    }
  }
}

__global__ void scene_cls(const float* __restrict__ cls, const float* __restrict__ pos,
                          float* __restrict__ scene) {
  int b = blockIdx.x;
  for (int e = threadIdx.x; e < E_DIM; e += 256)
    scene[(size_t)b * NTOK * E_DIM + e] = cls[e] + pos[e];
}

__global__ __launch_bounds__(256) void ln_rows(const float* __restrict__ in, float* __restrict__ out) {
  __shared__ float red[256];
  int r = blockIdx.x, tid = threadIdx.x;
  const float* x = in + (size_t)r * E_DIM;
  float a0 = x[tid], a1 = x[tid + 256], a2 = x[tid + 512];
  float mean = block_reduce_sum(a0 + a1 + a2, red) * (1.f / 768.f);
  float d0 = a0 - mean, d1 = a1 - mean, d2 = a2 - mean;
  float var = block_reduce_sum(d0 * d0 + d1 * d1 + d2 * d2, red) * (1.f / 768.f);
  float rinv = rsqrtf(var + 1e-5f);
  float* o = out + (size_t)r * E_DIM;
  o[tid] = d0 * rinv; o[tid + 256] = d1 * rinv; o[tid + 512] = d2 * rinv;
}

__global__ __launch_bounds__(256) void tgt_init(
    const float* __restrict__ tmask, const float* __restrict__ W,
    const float* __restrict__ bias, const float* __restrict__ cls,
    const float* __restrict__ tpos, float* __restrict__ tq) {
  int b = blockIdx.x, tid = threadIdx.x;
  for (int e = tid; e < E_DIM; e += 256)
    tq[(size_t)(b * 2) * E_DIM + e] = cls[e] + tpos[e];
  const float* tm = tmask + (size_t)b * P2;
  for (int e = tid; e < E_DIM; e += 256) {
    const float* wr = W + (size_t)e * P2;
    float s = 0.f;
    for (int k = 0; k < P2; k += 4) {
      float4 w4 = *(const float4*)&wr[k];
      float4 t4 = *(const float4*)&tm[k];
      s += w4.x * t4.x + w4.y * t4.y + w4.z * t4.z + w4.w * t4.w;
    }
    tq[(size_t)(b * 2 + 1) * E_DIM + e] = s + bias[e] + tpos[E_DIM + e];
  }
}

__global__ void prep_m(const float* __restrict__ Wq, const float* __restrict__ Wk,
                       float* __restrict__ Mb) {
  int l = blockIdx.y;
  int idx = blockIdx.x * 256 + threadIdx.x;
  int d = idx >> 6, dp = idx & 63;
  const float* wq = Wq + l * 4096;
  const float* wk = Wk + l * 4096;
  float s = 0.f;
#pragma unroll 8
  for (int e = 0; e < 64; ++e) s += wq[e * 64 + d] * wk[e * 64 + dp];
  Mb[l * 4096 + idx] = s;
}

__global__ void prep_wvo(const float* __restrict__ Wv, const float* __restrict__ Wo,
                         float* __restrict__ Wvo) {
  int l = blockIdx.y;
  int idx = blockIdx.x * 256 + threadIdx.x;
  int ep = idx / 768, hd = idx % 768;
  int h = hd >> 6, d = hd & 63;
  const float* wv = Wv + (size_t)l * 4096;
  const float* wo = Wo + (size_t)l * 768 * 768 + (size_t)ep * 768 + h * 64;
  float s = 0.f;
#pragma unroll 8
  for (int ev = 0; ev < 64; ++ev) s += wv[ev * 64 + d] * wo[ev];
  Wvo[(size_t)l * 589824 + idx] = s;
}

// ---------------- attn: fused LN2-prologue + q-LN/qproj + flash + out-proj epilogue ----------------
// from_part==1: y = LN2(sum_{i<16} partFF + fb2 + xres), reduce_ln's exact op order;
//               h==0 writes tq_out. Epilogue: per-head out-proj partial -> partC[h].
#define ACH 272
__global__ __launch_bounds__(256) void attn_flash_q(
    const float* __restrict__ tq_in, const float* __restrict__ partFF,
    const float* __restrict__ fb2l, const float* __restrict__ g2l,
    const float* __restrict__ b2l, const float* __restrict__ xres,
    int from_part, float* __restrict__ tq_out,
    const float* __restrict__ Mb, const float* __restrict__ g1,
    const float* __restrict__ b1, int l,
    const float* __restrict__ ns, const float* __restrict__ Wvo_l,
    float* __restrict__ partC) {
  __shared__ float red[256];
  __shared__ float qs[2][64];
  __shared__ float qg[2][64];
  __shared__ float qmb[2];
  __shared__ float sred[2][16];
  __shared__ float cred[2][16][64];
  __shared__ float ctxs[2][64];
  __shared__ float pr[2][768];
  int b = blockIdx.x / NHEADS;
  int h = blockIdx.x % NHEADS;
  int tid = threadIdx.x;
  const float* gl = g1 + l * E_DIM;
  const float* bl = b1 + l * E_DIM;
  int seg = h >> 2;
  int base = h * 64 - seg * 256;

  // ---- obtain y rows (tq of this layer) ----
  float y[2][3];
  if (!from_part) {
#pragma unroll
    for (int r = 0; r < 2; ++r) {
      const float* x = tq_in + (size_t)(b * 2 + r) * E_DIM;
      y[r][0] = x[tid]; y[r][1] = x[tid + 256]; y[r][2] = x[tid + 512];
    }
  } else {
#pragma unroll
    for (int r = 0; r < 2; ++r) {
      int m = b * 2 + r;
      float t[3];
#pragma unroll
      for (int c = 0; c < 3; ++c) {
        int n = tid + c * 256;
        float s = 0.f;
        for (int i = 0; i < 16; ++i) s += partFF[((size_t)i * 64 + m) * 768 + n];
        t[c] = s + fb2l[n] + xres[(size_t)m * 768 + n];
      }
      float mean = block_reduce_sum(t[0] + t[1] + t[2], red) * (1.f / 768.f);
      float d0 = t[0] - mean, d1 = t[1] - mean, d2 = t[2] - mean;
      float var = block_reduce_sum(d0 * d0 + d1 * d1 + d2 * d2, red) * (1.f / 768.f);
      float rinv = rsqrtf(var + 1e-5f);
      y[r][0] = d0 * rinv * g2l[tid] + b2l[tid];
      y[r][1] = d1 * rinv * g2l[tid + 256] + b2l[tid + 256];
      y[r][2] = d2 * rinv * g2l[tid + 512] + b2l[tid + 512];
      if (h == 0) {
        tq_out[(size_t)m * E_DIM + tid] = y[r][0];
        tq_out[(size_t)m * E_DIM + tid + 256] = y[r][1];
        tq_out[(size_t)m * E_DIM + tid + 512] = y[r][2];
      }
    }
  }

  // ---- q-LN (LN1) + q-projection ----
  for (int r = 0; r < 2; ++r) {
    float a0 = y[r][0], a1 = y[r][1], a2 = y[r][2];
    float mean = block_reduce_sum(a0 + a1 + a2, red) * (1.f / 768.f);
    float d0 = a0 - mean, d1 = a1 - mean, d2 = a2 - mean;
    float var = block_reduce_sum(d0 * d0 + d1 * d1 + d2 * d2, red) * (1.f / 768.f);
    float rinv = rsqrtf(var + 1e-5f);
    float dv = (seg == 0) ? d0 : ((seg == 1) ? d1 : d2);
    if (tid >= base && tid < base + 64) {
      int d = tid - base;
      qs[r][d] = dv * rinv * gl[h * 64 + d] + bl[h * 64 + d];
    }
  }
  __syncthreads();
  const float inv_scale = rsqrtf(768.f);
  if (tid < 128) {
    int r = tid >> 6, dp = tid & 63;
    const float* M = Mb + l * 4096;
    float s = 0.f;
#pragma unroll 8
    for (int d = 0; d < 64; ++d) s += qs[r][d] * M[d * 64 + dp];
    qg[r][dp] = s * gl[h * 64 + dp] * inv_scale;
    red[tid] = s * bl[h * 64 + dp];
  }
  __syncthreads();
  if (tid < 2) {
    float a = 0.f;
    for (int dp = 0; dp < 64; ++dp) a += red[tid * 64 + dp];
    qmb[tid] = a * inv_scale;
  }
  __syncthreads();
  int g = tid >> 4;
  int lane = tid & 15;
  int r0 = b * 2, r1 = r0 + 1;
  const float* nsb = ns + (size_t)b * NTOK * E_DIM + h * 64;
  float4 q0v = *(const float4*)&qg[0][lane * 4];
  float4 q1v = *(const float4*)&qg[1][lane * 4];
  float qb0 = qmb[0], qb1 = qmb[1];
  float m = -1e30f, s0 = 0.f, s1 = 0.f;
  float4 c0 = {0, 0, 0, 0}, c1 = {0, 0, 0, 0};
  float4 v[17];
  float e0a[17], e1a[17];
  for (int cb = 0; cb < NTOK; cb += ACH) {
    int ntk = NTOK - cb; if (ntk > ACH) ntk = ACH;
    int cnt = (ntk - g + 15) >> 4;
    float mloc = -1e30f;
#pragma unroll
    for (int i = 0; i < 17; ++i) {
      if (i < cnt) {
        int k = cb + g + (i << 4);
        float4 vv = *(const float4*)(nsb + (size_t)k * E_DIM + lane * 4);
        v[i] = vv;
        float p0 = vv.x * q0v.x + vv.y * q0v.y + vv.z * q0v.z + vv.w * q0v.w;
        float p1 = vv.x * q1v.x + vv.y * q1v.y + vv.z * q1v.z + vv.w * q1v.w;
#pragma unroll
        for (int off = 8; off; off >>= 1) {
          p0 += __shfl_xor(p0, off, 16);
          p1 += __shfl_xor(p1, off, 16);
        }
        float e0 = p0 + qb0, e1 = p1 + qb1;
        e0a[i] = e0; e1a[i] = e1;
        mloc = fmaxf(mloc, fmaxf(e0, e1));
      }
    }
    red[tid] = mloc;
    __syncthreads();
#pragma unroll
    for (int s = 128; s > 0; s >>= 1) {
      if (tid < s) red[tid] = fmaxf(red[tid], red[tid + s]);
      __syncthreads();
    }
    float mnew = fmaxf(m, red[0]);
    __syncthreads();
    if (mnew > m) {
      float f = expf(m - mnew);
      s0 *= f; s1 *= f;
      c0.x *= f; c0.y *= f; c0.z *= f; c0.w *= f;
      c1.x *= f; c1.y *= f; c1.z *= f; c1.w *= f;
      m = mnew;
    }
#pragma unroll
    for (int i = 0; i < 17; ++i) {
      if (i < cnt) {
        float p0 = expf(e0a[i] - m);
        float p1 = expf(e1a[i] - m);
        s0 += p0; s1 += p1;
        c0.x += p0 * v[i].x; c0.y += p0 * v[i].y; c0.z += p0 * v[i].z; c0.w += p0 * v[i].w;
        c1.x += p1 * v[i].x; c1.y += p1 * v[i].y; c1.z += p1 * v[i].z; c1.w += p1 * v[i].w;
      }
    }
  }
  if (lane == 0) { sred[0][g] = s0; sred[1][g] = s1; }
  *(float4*)&cred[0][g][lane * 4] = c0;
  *(float4*)&cred[1][g][lane * 4] = c1;
  __syncthreads();
  if (tid < 128) {
    int t = tid >> 6, dd = tid & 63;
    int o = h * 64 + dd;
    float stot = 0.f, cs = 0.f;
#pragma unroll
    for (int gg = 0; gg < 16; ++gg) { stot += sred[t][gg]; cs += cred[t][gg][dd]; }
    float inv = 1.f / stot;
    // v carries LN gamma/beta (softmax sums to 1): ctx = (att.ns)*g + b
    ctxs[t][dd] = cs * inv * gl[o] + bl[o];
  }
  __syncthreads();
  // ---- out-proj epilogue (r12 GEMV, partial write instead of atomics) ----
  const float* wbase = Wvo_l + (size_t)h * 64 + lane * 4;
  float4 x0 = *(const float4*)&ctxs[0][lane * 4];
  float4 x1 = *(const float4*)&ctxs[1][lane * 4];
  for (int n = g; n < 768; n += 16) {
    float4 wv = *(const float4*)(wbase + (size_t)n * 768);
    float a0 = wv.x * x0.x + wv.y * x0.y + wv.z * x0.z + wv.w * x0.w;
    float a1 = wv.x * x1.x + wv.y * x1.y + wv.z * x1.z + wv.w * x1.w;
#pragma unroll
    for (int off = 8; off; off >>= 1) {
      a0 += __shfl_xor(a0, off, 16);
      a1 += __shfl_xor(a1, off, 16);
    }
    if (lane == 0) { pr[0][n] = a0; pr[1][n] = a1; }
  }
  __syncthreads();
  float* pc = partC + (size_t)h * 49152;  // [h][64][768]
  for (int i = tid; i < 2 * 768; i += 256) {
    int r = i / 768, c = i % 768;
    pc[(size_t)(r0 + r) * 768 + c] = pr[r][c];
  }
}

// ---------------- skinny GEMM (M=64) partial over k-chunk (r6-proven) ----------------
__global__ __launch_bounds__(256) void skinny_part(
    const float* __restrict__ X, int K, const float* __restrict__ W,
    int kchunk, float* __restrict__ part, int N) {
  __shared__ float Xs[16][64];
  __shared__ float Ws[16][64];
  int tid = threadIdx.x;
  int n0 = blockIdx.x * 64;
  int s = blockIdx.y;
  int kbeg = s * kchunk;
  int lr = tid >> 2;
  int lk = (tid & 3) << 2;
  int ty = tid >> 4, tx = tid & 15;
  float acc[4][4] = {};
  for (int k0 = kbeg; k0 < kbeg + kchunk; k0 += 16) {
    float4 xv = *(const float4*)(X + (size_t)lr * K + k0 + lk);
    float4 wv = *(const float4*)(W + (size_t)(n0 + lr) * K + k0 + lk);
    __syncthreads();
    Xs[lk + 0][lr] = xv.x; Xs[lk + 1][lr] = xv.y; Xs[lk + 2][lr] = xv.z; Xs[lk + 3][lr] = xv.w;
    Ws[lk + 0][lr] = wv.x; Ws[lk + 1][lr] = wv.y; Ws[lk + 2][lr] = wv.z; Ws[lk + 3][lr] = wv.w;
    __syncthreads();
#pragma unroll
    for (int kk = 0; kk < 16; ++kk) {
      float4 a4 = *(const float4*)&Xs[kk][ty << 2];
      float4 b4 = *(const float4*)&Ws[kk][tx << 2];
      float av[4] = {a4.x, a4.y, a4.z, a4.w};
      float bv[4] = {b4.x, b4.y, b4.z, b4.w};
#pragma unroll
      for (int i = 0; i < 4; ++i)
#pragma unroll
        for (int j = 0; j < 4; ++j) acc[i][j] += av[i] * bv[j];
    }
  }
#pragma unroll
  for (int i = 0; i < 4; ++i) {
    int mm = (ty << 2) + i;
    float4 o4 = make_float4(acc[i][0], acc[i][1], acc[i][2], acc[i][3]);
    *(float4*)&part[((size_t)s * 64 + mm) * N + n0 + (tx << 2)] = o4;
  }
}

// FF2 skinny: X = relu(sum_{s<4} part1[s] + b1) computed inline (K=3072) (r6-proven)
__global__ __launch_bounds__(256) void skinny_h1_part(
    const float* __restrict__ part1, const float* __restrict__ b1,
    const float* __restrict__ W, int kchunk, float* __restrict__ part2) {
  __shared__ float Xs[16][64];
  __shared__ float Ws[16][64];
  const int K = 3072, N = 768;
  int tid = threadIdx.x;
  int n0 = blockIdx.x * 64;
  int s = blockIdx.y;
  int kbeg = s * kchunk;
  int lr = tid >> 2;
  int lk = (tid & 3) << 2;
  int ty = tid >> 4, tx = tid & 15;
  float acc[4][4] = {};
  for (int k0 = kbeg; k0 < kbeg + kchunk; k0 += 16) {
    float4 x0 = *(const float4*)(part1 + (size_t)lr * K + k0 + lk);
    float4 x1 = *(const float4*)(part1 + (size_t)(64 + lr) * K + k0 + lk);
    float4 x2 = *(const float4*)(part1 + (size_t)(128 + lr) * K + k0 + lk);
    float4 x3 = *(const float4*)(part1 + (size_t)(192 + lr) * K + k0 + lk);
    float4 bb = *(const float4*)(b1 + k0 + lk);
    float4 xv;
    xv.x = fmaxf(x0.x + x1.x + x2.x + x3.x + bb.x, 0.f);
    xv.y = fmaxf(x0.y + x1.y + x2.y + x3.y + bb.y, 0.f);
    xv.z = fmaxf(x0.z + x1.z + x2.z + x3.z + bb.z, 0.f);
    xv.w = fmaxf(x0.w + x1.w + x2.w + x3.w + bb.w, 0.f);
    float4 wv = *(const float4*)(W + (size_t)(n0 + lr) * K + k0 + lk);
    __syncthreads();
    Xs[lk + 0][lr] = xv.x; Xs[lk + 1][lr] = xv.y; Xs[lk + 2][lr] = xv.z; Xs[lk + 3][lr] = xv.w;
    Ws[lk + 0][lr] = wv.x; Ws[lk + 1][lr] = wv.y; Ws[lk + 2][lr] = wv.z; Ws[lk + 3][lr] = wv.w;
    __syncthreads();
#pragma unroll
    for (int kk = 0; kk < 16; ++kk) {
      float4 a4 = *(const float4*)&Xs[kk][ty << 2];
      float4 b4 = *(const float4*)&Ws[kk][tx << 2];
      float av[4] = {a4.x, a4.y, a4.z, a4.w};
      float bv[4] = {b4.x, b4.y, b4.z, b4.w};
#pragma unroll
      for (int i = 0; i < 4; ++i)
#pragma unroll
        for (int j = 0; j < 4; ++j) acc[i][j] += av[i] * bv[j];
    }
  }
#pragma unroll
  for (int i = 0; i < 4; ++i) {
    int mm = (ty << 2) + i;
    float4 o4 = make_float4(acc[i][0], acc[i][1], acc[i][2], acc[i][3]);
    *(float4*)&part2[((size_t)s * 64 + mm) * N + n0 + (tx << 2)] = o4;
  }
}

// reduce partials + bias + residual + LN; optional xm accumulation (r11-validated)
__global__ __launch_bounds__(256) void reduce_ln(
    const float* __restrict__ part, int S, const float* __restrict__ bias,
    const float* __restrict__ res, const float* __restrict__ g,
    const float* __restrict__ bsh, float* __restrict__ out,
    float* __restrict__ xmean) {
  __shared__ float red[256];
  int m = blockIdx.x, tid = threadIdx.x;
  float t[3];
#pragma unroll
  for (int c = 0; c < 3; ++c) {
    int n = tid + c * 256;
    float s = 0.f;
    for (int i = 0; i < S; ++i) s += part[((size_t)i * 64 + m) * 768 + n];
    t[c] = s + bias[n] + res[(size_t)m * 768 + n];
  }
  float mean = block_reduce_sum(t[0] + t[1] + t[2], red) * (1.f / 768.f);
  float d0 = t[0] - mean, d1 = t[1] - mean, d2 = t[2] - mean;
  float var = block_reduce_sum(d0 * d0 + d1 * d1 + d2 * d2, red) * (1.f / 768.f);
  float rinv = rsqrtf(var + 1e-5f);
  float y0 = d0 * rinv * g[tid] + bsh[tid];
  float y1 = d1 * rinv * g[tid + 256] + bsh[tid + 256];
  float y2 = d2 * rinv * g[tid + 512] + bsh[tid + 512];
  out[(size_t)m * 768 + tid] = y0;
  out[(size_t)m * 768 + tid + 256] = y1;
  out[(size_t)m * 768 + tid + 512] = y2;
  if (xmean) {
    float* xr = xmean + (size_t)(m >> 1) * 768;
    atomicAdd(&xr[tid], 0.5f * y0);
    atomicAdd(&xr[tid + 256], 0.5f * y1);
    atomicAdd(&xr[tid + 512], 0.5f * y2);
  }
}

// head: logits row from 4 partials + bias, then top-5 one-hot (r6-proven)
__global__ __launch_bounds__(256) void top5_from_parts(
    const float* __restrict__ part, const float* __restrict__ bias,
    float* __restrict__ out) {
  __shared__ float v[1024];
  __shared__ float bv[256];
  __shared__ int bi[256];
  int b = blockIdx.x, tid = threadIdx.x;
  for (int i = tid; i < 1024; i += 256) {
    float s = part[(size_t)(0 * 64 + b) * 1024 + i] + part[(size_t)(1 * 64 + b) * 1024 + i] +
              part[(size_t)(2 * 64 + b) * 1024 + i] + part[(size_t)(3 * 64 + b) * 1024 + i];
    v[i] = s + bias[i];
  }
  float* ob = out + (size_t)b * 5 * NTOK;
  for (int i = tid; i < 5 * NTOK; i += 256) ob[i] = 0.f;
  __syncthreads();
  for (int it = 0; it < 5; ++it) {
    float best = -1e38f;
    int bidx = 0x7fffffff;
    for (int i = tid; i < 1024; i += 256) {
      float x = v[i];
      if (x > best || (x == best && i < bidx)) { best = x; bidx = i; }
    }
    bv[tid] = best; bi[tid] = bidx;
    __syncthreads();
    for (int s = 128; s > 0; s >>= 1) {
      if (tid < s) {
        if (bv[tid + s] > bv[tid] || (bv[tid + s] == bv[tid] && bi[tid + s] < bi[tid])) {
          bv[tid] = bv[tid + s]; bi[tid] = bi[tid + s];
        }
      }
      __syncthreads();
    }
    if (tid == 0) {
      ob[it * NTOK + bi[0]] = 1.0f;
      v[bi[0]] = -1e38f;
    }
    __syncthreads();
  }
}

extern "C" void kernel_launch(void* const* d_in, const int* in_sizes, int n_in,
                              void* d_out, int out_size, void* d_ws, size_t ws_size,
                              hipStream_t stream) {
  const float* scene_masks = (const float*)d_in[0];
  const float* target_mask = (const float*)d_in[1];
  const float* emb_W = (const float*)d_in[2];
  const float* emb_b = (const float*)d_in[3];
  const float* class_embed = (const float*)d_in[4];
  const float* scene_pos = (const float*)d_in[5];
  const float* target_pos = (const float*)d_in[6];
  const float* ln1_g = (const float*)d_in[7];
  const float* ln1_b = (const float*)d_in[8];
  const float* ln2_g = (const float*)d_in[9];
  const float* ln2_b = (const float*)d_in[10];
  const float* Wq = (const float*)d_in[11];
  const float* Wk = (const float*)d_in[12];
  const float* Wv = (const float*)d_in[13];
  const float* Wo = (const float*)d_in[14];
  const float* bo = (const float*)d_in[15];
  const float* W1 = (const float*)d_in[16];
  const float* fb1 = (const float*)d_in[17];
  const float* W2 = (const float*)d_in[18];
  const float* fb2 = (const float*)d_in[19];
  const float* mlp_W = (const float*)d_in[20];
  const float* mlp_b = (const float*)d_in[21];
  float* out = (float*)d_out;

  float* ws = (float*)d_ws;
  float* scene = ws;                       // 25190400
  float* Mbuf = scene + 25190400;          // 49152
  float* Wvo = Mbuf + 49152;               // 7077888
  float* tq = Wvo + 7077888;               // 49152
  float* xbuf = tq + 49152;                // 49152
  float* xm = xbuf + 49152;                // 49152 (zeroed; rows>=32 stay 0)
  float* partA = xm + 49152;               // 786432 (FF2: 16x64x768)
  float* partB = partA + 786432;           // 786432 (FF1: 4x64x3072)
  float* partC = partB + 786432;           // 589824 (attn out-proj: 12x64x768)

  // ---- setup ----
  embed_gemm<<<1536, 256, 0, stream>>>(scene_masks, emb_W, emb_b, scene_pos, scene);
  scene_cls<<<32, 256, 0, stream>>>(class_embed, scene_pos, scene);
  ln_rows<<<32 * NTOK, 256, 0, stream>>>(scene, scene);
  tgt_init<<<32, 256, 0, stream>>>(target_mask, emb_W, emb_b, class_embed, target_pos, tq);
  prep_m<<<dim3(16, 12), 256, 0, stream>>>(Wq, Wk, Mbuf);
  prep_wvo<<<dim3(2304, 12), 256, 0, stream>>>(Wv, Wo, Wvo);
  hipMemsetAsync(xm, 0, 49152 * sizeof(float), stream);

  // ---- 12 transformer blocks: 4 launches/layer ----
  for (int l = 0; l < LAYERS; ++l) {
    if (l == 0)
      attn_flash_q<<<32 * NHEADS, 256, 0, stream>>>(
          tq, nullptr, nullptr, nullptr, nullptr, nullptr, 0, nullptr,
          Mbuf, ln1_g, ln1_b, l, scene, Wvo + (size_t)l * 589824, partC);
    else
      attn_flash_q<<<32 * NHEADS, 256, 0, stream>>>(
          nullptr, partA, fb2 + (l - 1) * 768, ln2_g + (l - 1) * 768,
          ln2_b + (l - 1) * 768, xbuf, 1, tq,
          Mbuf, ln1_g, ln1_b, l, scene, Wvo + (size_t)l * 589824, partC);
    // x = LN1(sum_{h<12} partC + bo + tq)
    reduce_ln<<<64, 256, 0, stream>>>(partC, 12, bo + l * 768, tq,
                                      ln1_g + l * 768, ln1_b + l * 768, xbuf, nullptr);
    // FF1 partials -> partB
    skinny_part<<<dim3(48, 4), 256, 0, stream>>>(xbuf, 768, W1 + (size_t)l * FF_DIM * 768, 192, partB, FF_DIM);
    // FF2 (inline h1 = relu(sum+b1)) -> partA  [consumed by attn(l+1) or final LN2]
    skinny_h1_part<<<dim3(12, 16), 256, 0, stream>>>(partB, fb1 + l * FF_DIM,
                                                     W2 + (size_t)l * 768 * FF_DIM, 192, partA);
  }
  // final LN2 (l=11): S=16 partials -> tq + xm accumulation
  reduce_ln<<<64, 256, 0, stream>>>(partA, 16, fb2 + 11 * 768, xbuf,
                                    ln2_g + 11 * 768, ln2_b + 11 * 768, tq, xm);

  // ---- head ----
  skinny_part<<<dim3(16, 4), 256, 0, stream>>>(xm, 768, mlp_W, 192, partA, 1024);
  top5_from_parts<<<32, 256, 0, stream>>>(partA, mlp_b, out);
}

// Round 18
// 1815.367 us; speedup vs baseline: 1.1349x; 1.1349x over previous
//
#include <hip/hip_runtime.h>
#include <math.h>

#define E_DIM 768
#define NTOK 1025
#define B_DIM 32
#define NHEADS 12
#define HDIM 64
#define LAYERS 12
#define FF_DIM 3072
#define P2 576

// ---------------- helpers ----------------
__device__ __forceinline__ float block_reduce_sum(float v, float* red) {
  int tid = threadIdx.x;
  red[tid] = v;
  __syncthreads();
#pragma unroll
  for (int s = 128; s > 0; s >>= 1) {
    if (tid < s) red[tid] += red[tid + s];
    __syncthreads();
  }
  float r = red[0];
  __syncthreads();
  return r;
}

// ---------------- embed GEMM: 128x128 tile, 8x8 acc, XCD-swizzled (r14) ----------------
__global__ __launch_bounds__(256) void embed_gemm(
    const float* __restrict__ A, const float* __restrict__ W,
    const float* __restrict__ bias, const float* __restrict__ pos,
    float* __restrict__ scene) {
  __shared__ float Xs[16][132];
  __shared__ float Ws[16][132];
  int tid = threadIdx.x;
  int bid = blockIdx.x;
  int xcd = bid & 7;
  int idx = bid >> 3;
  int m_tile = xcd * 32 + idx / 6;
  int n_tile = idx % 6;
  int n0 = n_tile * 128;
  int m0 = m_tile * 128;
  int lr = tid >> 2;
  int lk = (tid & 3) << 2;
  int ty = tid >> 4, tx = tid & 15;
  float acc[8][8] = {};
  for (int k0 = 0; k0 < P2; k0 += 16) {
    float4 x0 = *(const float4*)(A + (size_t)(m0 + lr) * P2 + k0 + lk);
    float4 x1 = *(const float4*)(A + (size_t)(m0 + 64 + lr) * P2 + k0 + lk);
    float4 w0 = *(const float4*)(W + (size_t)(n0 + lr) * P2 + k0 + lk);
    float4 w1 = *(const float4*)(W + (size_t)(n0 + 64 + lr) * P2 + k0 + lk);
    __syncthreads();
    Xs[lk + 0][lr] = x0.x; Xs[lk + 1][lr] = x0.y; Xs[lk + 2][lr] = x0.z; Xs[lk + 3][lr] = x0.w;
    Xs[lk + 0][64 + lr] = x1.x; Xs[lk + 1][64 + lr] = x1.y; Xs[lk + 2][64 + lr] = x1.z; Xs[lk + 3][64 + lr] = x1.w;
    Ws[lk + 0][lr] = w0.x; Ws[lk + 1][lr] = w0.y; Ws[lk + 2][lr] = w0.z; Ws[lk + 3][lr] = w0.w;
    Ws[lk + 0][64 + lr] = w1.x; Ws[lk + 1][64 + lr] = w1.y; Ws[lk + 2][64 + lr] = w1.z; Ws[lk + 3][64 + lr] = w1.w;
    __syncthreads();
#pragma unroll
    for (int kk = 0; kk < 16; ++kk) {
      float4 a0 = *(const float4*)&Xs[kk][ty << 2];
      float4 a1 = *(const float4*)&Xs[kk][64 + (ty << 2)];
      float4 b0 = *(const float4*)&Ws[kk][tx << 2];
      float4 b1 = *(const float4*)&Ws[kk][64 + (tx << 2)];
      float av[8] = {a0.x, a0.y, a0.z, a0.w, a1.x, a1.y, a1.z, a1.w};
      float bv[8] = {b0.x, b0.y, b0.z, b0.w, b1.x, b1.y, b1.z, b1.w};
#pragma unroll
      for (int i = 0; i < 8; ++i)
#pragma unroll
        for (int j = 0; j < 8; ++j) acc[i][j] += av[i] * bv[j];
    }
  }
#pragma unroll
  for (int i = 0; i < 8; ++i) {
    int mloc = (i < 4) ? ((ty << 2) + i) : (64 + (ty << 2) + i - 4);
    int m = m0 + mloc;
    int b = m >> 10, nt = m & 1023;
    size_t row = ((size_t)b * NTOK + 1 + nt) * E_DIM;
    size_t prow = (size_t)(1 + nt) * E_DIM;
#pragma unroll
    for (int half = 0; half < 2; ++half) {
      int n = n0 + half * 64 + (tx << 2);
      float4 o4;
      o4.x = acc[i][half * 4 + 0] + bias[n + 0] + pos[prow + n + 0];
      o4.y = acc[i][half * 4 + 1] + bias[n + 1] + pos[prow + n + 1];
      o4.z = acc[i][half * 4 + 2] + bias[n + 2] + pos[prow + n + 2];
      o4.w = acc[i][half * 4 + 3] + bias[n + 3] + pos[prow + n + 3];
      *(float4*)&scene[row + n] = o4;
    }
  }
}

// normalize row; cls rows (nt==0) computed inline from cls+pos (bit-identical to
// the old scene_cls write + read)
__global__ __launch_bounds__(256) void ln_rows(
    const float* __restrict__ in, float* __restrict__ out,
    const float* __restrict__ cls, const float* __restrict__ pos) {
  __shared__ float red[256];
  int r = blockIdx.x, tid = threadIdx.x;
  int nt = r % NTOK;
  float a0, a1, a2;
  if (nt == 0) {
    a0 = cls[tid] + pos[tid];
    a1 = cls[tid + 256] + pos[tid + 256];
    a2 = cls[tid + 512] + pos[tid + 512];
  } else {
    const float* x = in + (size_t)r * E_DIM;
    a0 = x[tid]; a1 = x[tid + 256]; a2 = x[tid + 512];
  }
  float mean = block_reduce_sum(a0 + a1 + a2, red) * (1.f / 768.f);
  float d0 = a0 - mean, d1 = a1 - mean, d2 = a2 - mean;
  float var = block_reduce_sum(d0 * d0 + d1 * d1 + d2 * d2, red) * (1.f / 768.f);
  float rinv = rsqrtf(var + 1e-5f);
  float* o = out + (size_t)r * E_DIM;
  o[tid] = d0 * rinv; o[tid + 256] = d1 * rinv; o[tid + 512] = d2 * rinv;
}

__global__ __launch_bounds__(256) void tgt_init(
    const float* __restrict__ tmask, const float* __restrict__ W,
    const float* __restrict__ bias, const float* __restrict__ cls,
    const float* __restrict__ tpos, float* __restrict__ tq) {
  int b = blockIdx.x, tid = threadIdx.x;
  for (int e = tid; e < E_DIM; e += 256)
    tq[(size_t)(b * 2) * E_DIM + e] = cls[e] + tpos[e];
  const float* tm = tmask + (size_t)b * P2;
  for (int e = tid; e < E_DIM; e += 256) {
    const float* wr = W + (size_t)e * P2;
    float s = 0.f;
    for (int k = 0; k < P2; k += 4) {
      float4 w4 = *(const float4*)&wr[k];
      float4 t4 = *(const float4*)&tm[k];
      s += w4.x * t4.x + w4.y * t4.y + w4.z * t4.z + w4.w * t4.w;
    }
    tq[(size_t)(b * 2 + 1) * E_DIM + e] = s + bias[e] + tpos[E_DIM + e];
  }
}

__global__ void prep_m(const float* __restrict__ Wq, const float* __restrict__ Wk,
                       float* __restrict__ Mb) {
  int l = blockIdx.y;
  int idx = blockIdx.x * 256 + threadIdx.x;
  int d = idx >> 6, dp = idx & 63;
  const float* wq = Wq + l * 4096;
  const float* wk = Wk + l * 4096;
  float s = 0.f;
#pragma unroll 8
  for (int e = 0; e < 64; ++e) s += wq[e * 64 + d] * wk[e * 64 + dp];
  Mb[l * 4096 + idx] = s;
}

__global__ void prep_wvo(const float* __restrict__ Wv, const float* __restrict__ Wo,
                         float* __restrict__ Wvo) {
  int l = blockIdx.y;
  int idx = blockIdx.x * 256 + threadIdx.x;
  int ep = idx / 768, hd = idx % 768;
  int h = hd >> 6, d = hd & 63;
  const float* wv = Wv + (size_t)l * 4096;
  const float* wo = Wo + (size_t)l * 768 * 768 + (size_t)ep * 768 + h * 64;
  float s = 0.f;
#pragma unroll 8
  for (int ev = 0; ev < 64; ++ev) s += wv[ev * 64 + d] * wo[ev];
  Wvo[(size_t)l * 589824 + idx] = s;
}

// ---------------- attn: fused LN2-of-prev-layer + q-LN/qproj + flash (r16) ----------------
// from_part==0: y rows read from tq_in (layer 0).
// from_part==1: y = LN2(sum_{i<16} partFF + fb2 + xres), reduce_ln's exact op order
//               (S=16 matches skinny_h1_part's dim3(12,16) launch); h==0 writes tq_out.
#define ACH 272
__global__ __launch_bounds__(256) void attn_flash_q(
    const float* __restrict__ tq_in, const float* __restrict__ partFF,
    const float* __restrict__ fb2l, const float* __restrict__ g2l,
    const float* __restrict__ b2l, const float* __restrict__ xres,
    int from_part, float* __restrict__ tq_out,
    const float* __restrict__ Mb, const float* __restrict__ g1,
    const float* __restrict__ b1, int l,
    const float* __restrict__ ns, float* __restrict__ ctx) {
  __shared__ float red[256];
  __shared__ float qs[2][64];
  __shared__ float qg[2][64];
  __shared__ float qmb[2];
  __shared__ float sred[2][16];
  __shared__ float cred[2][16][64];
  int b = blockIdx.x / NHEADS;
  int h = blockIdx.x % NHEADS;
  int tid = threadIdx.x;
  const float* gl = g1 + l * E_DIM;
  const float* bl = b1 + l * E_DIM;
  int seg = h >> 2;
  int base = h * 64 - seg * 256;

  // ---- obtain y rows (tq of this layer) ----
  float y[2][3];
  if (!from_part) {
#pragma unroll
    for (int r = 0; r < 2; ++r) {
      const float* x = tq_in + (size_t)(b * 2 + r) * E_DIM;
      y[r][0] = x[tid]; y[r][1] = x[tid + 256]; y[r][2] = x[tid + 512];
    }
  } else {
#pragma unroll
    for (int r = 0; r < 2; ++r) {
      int m = b * 2 + r;
      float t[3];
#pragma unroll
      for (int c = 0; c < 3; ++c) {
        int n = tid + c * 256;
        float s = 0.f;
        for (int i = 0; i < 16; ++i) s += partFF[((size_t)i * 64 + m) * 768 + n];
        t[c] = s + fb2l[n] + xres[(size_t)m * 768 + n];
      }
      float mean = block_reduce_sum(t[0] + t[1] + t[2], red) * (1.f / 768.f);
      float d0 = t[0] - mean, d1 = t[1] - mean, d2 = t[2] - mean;
      float var = block_reduce_sum(d0 * d0 + d1 * d1 + d2 * d2, red) * (1.f / 768.f);
      float rinv = rsqrtf(var + 1e-5f);
      y[r][0] = d0 * rinv * g2l[tid] + b2l[tid];
      y[r][1] = d1 * rinv * g2l[tid + 256] + b2l[tid + 256];
      y[r][2] = d2 * rinv * g2l[tid + 512] + b2l[tid + 512];
      if (h == 0) {
        tq_out[(size_t)m * E_DIM + tid] = y[r][0];
        tq_out[(size_t)m * E_DIM + tid + 256] = y[r][1];
        tq_out[(size_t)m * E_DIM + tid + 512] = y[r][2];
      }
    }
  }

  // ---- q-LN (LN1) + q-projection (r11-validated structure) ----
  for (int r = 0; r < 2; ++r) {
    float a0 = y[r][0], a1 = y[r][1], a2 = y[r][2];
    float mean = block_reduce_sum(a0 + a1 + a2, red) * (1.f / 768.f);
    float d0 = a0 - mean, d1 = a1 - mean, d2 = a2 - mean;
    float var = block_reduce_sum(d0 * d0 + d1 * d1 + d2 * d2, red) * (1.f / 768.f);
    float rinv = rsqrtf(var + 1e-5f);
    float dv = (seg == 0) ? d0 : ((seg == 1) ? d1 : d2);
    if (tid >= base && tid < base + 64) {
      int d = tid - base;
      qs[r][d] = dv * rinv * gl[h * 64 + d] + bl[h * 64 + d];
    }
  }
  __syncthreads();
  const float inv_scale = rsqrtf(768.f);
  if (tid < 128) {
    int r = tid >> 6, dp = tid & 63;
    const float* M = Mb + l * 4096;
    float s = 0.f;
#pragma unroll 8
    for (int d = 0; d < 64; ++d) s += qs[r][d] * M[d * 64 + dp];
    qg[r][dp] = s * gl[h * 64 + dp] * inv_scale;
    red[tid] = s * bl[h * 64 + dp];
  }
  __syncthreads();
  if (tid < 2) {
    float a = 0.f;
    for (int dp = 0; dp < 64; ++dp) a += red[tid * 64 + dp];
    qmb[tid] = a * inv_scale;
  }
  __syncthreads();
  int g = tid >> 4;
  int lane = tid & 15;
  int r0 = b * 2, r1 = r0 + 1;
  const float* nsb = ns + (size_t)b * NTOK * E_DIM + h * 64;
  float4 q0v = *(const float4*)&qg[0][lane * 4];
  float4 q1v = *(const float4*)&qg[1][lane * 4];
  float qb0 = qmb[0], qb1 = qmb[1];
  float m = -1e30f, s0 = 0.f, s1 = 0.f;
  float4 c0 = {0, 0, 0, 0}, c1 = {0, 0, 0, 0};
  float4 v[17];
  float e0a[17], e1a[17];
  for (int cb = 0; cb < NTOK; cb += ACH) {
    int ntk = NTOK - cb; if (ntk > ACH) ntk = ACH;
    int cnt = (ntk - g + 15) >> 4;
    float mloc = -1e30f;
#pragma unroll
    for (int i = 0; i < 17; ++i) {
      if (i < cnt) {
        int k = cb + g + (i << 4);
        float4 vv = *(const float4*)(nsb + (size_t)k * E_DIM + lane * 4);
        v[i] = vv;
        float p0 = vv.x * q0v.x + vv.y * q0v.y + vv.z * q0v.z + vv.w * q0v.w;
        float p1 = vv.x * q1v.x + vv.y * q1v.y + vv.z * q1v.z + vv.w * q1v.w;
#pragma unroll
        for (int off = 8; off; off >>= 1) {
          p0 += __shfl_xor(p0, off, 16);
          p1 += __shfl_xor(p1, off, 16);
        }
        float e0 = p0 + qb0, e1 = p1 + qb1;
        e0a[i] = e0; e1a[i] = e1;
        mloc = fmaxf(mloc, fmaxf(e0, e1));
      }
    }
    red[tid] = mloc;
    __syncthreads();
#pragma unroll
    for (int s = 128; s > 0; s >>= 1) {
      if (tid < s) red[tid] = fmaxf(red[tid], red[tid + s]);
      __syncthreads();
    }
    float mnew = fmaxf(m, red[0]);
    __syncthreads();
    if (mnew > m) {
      float f = expf(m - mnew);
      s0 *= f; s1 *= f;
      c0.x *= f; c0.y *= f; c0.z *= f; c0.w *= f;
      c1.x *= f; c1.y *= f; c1.z *= f; c1.w *= f;
      m = mnew;
    }
#pragma unroll
    for (int i = 0; i < 17; ++i) {
      if (i < cnt) {
        float p0 = expf(e0a[i] - m);
        float p1 = expf(e1a[i] - m);
        s0 += p0; s1 += p1;
        c0.x += p0 * v[i].x; c0.y += p0 * v[i].y; c0.z += p0 * v[i].z; c0.w += p0 * v[i].w;
        c1.x += p1 * v[i].x; c1.y += p1 * v[i].y; c1.z += p1 * v[i].z; c1.w += p1 * v[i].w;
      }
    }
  }
  if (lane == 0) { sred[0][g] = s0; sred[1][g] = s1; }
  *(float4*)&cred[0][g][lane * 4] = c0;
  *(float4*)&cred[1][g][lane * 4] = c1;
  __syncthreads();
  if (tid < 128) {
    int t = tid >> 6, dd = tid & 63;
    int o = h * 64 + dd;
    float stot = 0.f, cs = 0.f;
#pragma unroll
    for (int gg = 0; gg < 16; ++gg) { stot += sred[t][gg]; cs += cred[t][gg][dd]; }
    float inv = 1.f / stot;
    ctx[(size_t)(r0 + t) * E_DIM + o] = cs * inv * gl[o] + bl[o];
  }
}

// ---------------- skinny GEMM (M=64) partial over k-chunk (r6-proven) ----------------
__global__ __launch_bounds__(256) void skinny_part(
    const float* __restrict__ X, int K, const float* __restrict__ W,
    int kchunk, float* __restrict__ part, int N) {
  __shared__ float Xs[16][64];
  __shared__ float Ws[16][64];
  int tid = threadIdx.x;
  int n0 = blockIdx.x * 64;
  int s = blockIdx.y;
  int kbeg = s * kchunk;
  int lr = tid >> 2;
  int lk = (tid & 3) << 2;
  int ty = tid >> 4, tx = tid & 15;
  float acc[4][4] = {};
  for (int k0 = kbeg; k0 < kbeg + kchunk; k0 += 16) {
    float4 xv = *(const float4*)(X + (size_t)lr * K + k0 + lk);
    float4 wv = *(const float4*)(W + (size_t)(n0 + lr) * K + k0 + lk);
    __syncthreads();
    Xs[lk + 0][lr] = xv.x; Xs[lk + 1][lr] = xv.y; Xs[lk + 2][lr] = xv.z; Xs[lk + 3][lr] = xv.w;
    Ws[lk + 0][lr] = wv.x; Ws[lk + 1][lr] = wv.y; Ws[lk + 2][lr] = wv.z; Ws[lk + 3][lr] = wv.w;
    __syncthreads();
#pragma unroll
    for (int kk = 0; kk < 16; ++kk) {
      float4 a4 = *(const float4*)&Xs[kk][ty << 2];
      float4 b4 = *(const float4*)&Ws[kk][tx << 2];
      float av[4] = {a4.x, a4.y, a4.z, a4.w};
      float bv[4] = {b4.x, b4.y, b4.z, b4.w};
#pragma unroll
      for (int i = 0; i < 4; ++i)
#pragma unroll
        for (int j = 0; j < 4; ++j) acc[i][j] += av[i] * bv[j];
    }
  }
#pragma unroll
  for (int i = 0; i < 4; ++i) {
    int mm = (ty << 2) + i;
    float4 o4 = make_float4(acc[i][0], acc[i][1], acc[i][2], acc[i][3]);
    *(float4*)&part[((size_t)s * 64 + mm) * N + n0 + (tx << 2)] = o4;
  }
}

// FF2 skinny: X = relu(sum_{s<4} part1[s] + b1) computed inline (K=3072) (r6-proven)
__global__ __launch_bounds__(256) void skinny_h1_part(
    const float* __restrict__ part1, const float* __restrict__ b1,
    const float* __restrict__ W, int kchunk, float* __restrict__ part2) {
  __shared__ float Xs[16][64];
  __shared__ float Ws[16][64];
  const int K = 3072, N = 768;
  int tid = threadIdx.x;
  int n0 = blockIdx.x * 64;
  int s = blockIdx.y;
  int kbeg = s * kchunk;
  int lr = tid >> 2;
  int lk = (tid & 3) << 2;
  int ty = tid >> 4, tx = tid & 15;
  float acc[4][4] = {};
  for (int k0 = kbeg; k0 < kbeg + kchunk; k0 += 16) {
    float4 x0 = *(const float4*)(part1 + (size_t)lr * K + k0 + lk);
    float4 x1 = *(const float4*)(part1 + (size_t)(64 + lr) * K + k0 + lk);
    float4 x2 = *(const float4*)(part1 + (size_t)(128 + lr) * K + k0 + lk);
    float4 x3 = *(const float4*)(part1 + (size_t)(192 + lr) * K + k0 + lk);
    float4 bb = *(const float4*)(b1 + k0 + lk);
    float4 xv;
    xv.x = fmaxf(x0.x + x1.x + x2.x + x3.x + bb.x, 0.f);
    xv.y = fmaxf(x0.y + x1.y + x2.y + x3.y + bb.y, 0.f);
    xv.z = fmaxf(x0.z + x1.z + x2.z + x3.z + bb.z, 0.f);
    xv.w = fmaxf(x0.w + x1.w + x2.w + x3.w + bb.w, 0.f);
    float4 wv = *(const float4*)(W + (size_t)(n0 + lr) * K + k0 + lk);
    __syncthreads();
    Xs[lk + 0][lr] = xv.x; Xs[lk + 1][lr] = xv.y; Xs[lk + 2][lr] = xv.z; Xs[lk + 3][lr] = xv.w;
    Ws[lk + 0][lr] = wv.x; Ws[lk + 1][lr] = wv.y; Ws[lk + 2][lr] = wv.z; Ws[lk + 3][lr] = wv.w;
    __syncthreads();
#pragma unroll
    for (int kk = 0; kk < 16; ++kk) {
      float4 a4 = *(const float4*)&Xs[kk][ty << 2];
      float4 b4 = *(const float4*)&Ws[kk][tx << 2];
      float av[4] = {a4.x, a4.y, a4.z, a4.w};
      float bv[4] = {b4.x, b4.y, b4.z, b4.w};
#pragma unroll
      for (int i = 0; i < 4; ++i)
#pragma unroll
        for (int j = 0; j < 4; ++j) acc[i][j] += av[i] * bv[j];
    }
  }
#pragma unroll
  for (int i = 0; i < 4; ++i) {
    int mm = (ty << 2) + i;
    float4 o4 = make_float4(acc[i][0], acc[i][1], acc[i][2], acc[i][3]);
    *(float4*)&part2[((size_t)s * 64 + mm) * N + n0 + (tx << 2)] = o4;
  }
}

// reduce partials + bias + residual + LN; optional xm accumulation (r11-validated)
__global__ __launch_bounds__(256) void reduce_ln(
    const float* __restrict__ part, int S, const float* __restrict__ bias,
    const float* __restrict__ res, const float* __restrict__ g,
    const float* __restrict__ bsh, float* __restrict__ out,
    float* __restrict__ xmean) {
  __shared__ float red[256];
  int m = blockIdx.x, tid = threadIdx.x;
  float t[3];
#pragma unroll
  for (int c = 0; c < 3; ++c) {
    int n = tid + c * 256;
    float s = 0.f;
    for (int i = 0; i < S; ++i) s += part[((size_t)i * 64 + m) * 768 + n];
    t[c] = s + bias[n] + res[(size_t)m * 768 + n];
  }
  float mean = block_reduce_sum(t[0] + t[1] + t[2], red) * (1.f / 768.f);
  float d0 = t[0] - mean, d1 = t[1] - mean, d2 = t[2] - mean;
  float var = block_reduce_sum(d0 * d0 + d1 * d1 + d2 * d2, red) * (1.f / 768.f);
  float rinv = rsqrtf(var + 1e-5f);
  float y0 = d0 * rinv * g[tid] + bsh[tid];
  float y1 = d1 * rinv * g[tid + 256] + bsh[tid + 256];
  float y2 = d2 * rinv * g[tid + 512] + bsh[tid + 512];
  out[(size_t)m * 768 + tid] = y0;
  out[(size_t)m * 768 + tid + 256] = y1;
  out[(size_t)m * 768 + tid + 512] = y2;
  if (xmean) {
    float* xr = xmean + (size_t)(m >> 1) * 768;
    atomicAdd(&xr[tid], 0.5f * y0);
    atomicAdd(&xr[tid + 256], 0.5f * y1);
    atomicAdd(&xr[tid + 512], 0.5f * y2);
  }
}

// head: logits row from 4 partials + bias, then top-5 one-hot (r6-proven)
__global__ __launch_bounds__(256) void top5_from_parts(
    const float* __restrict__ part, const float* __restrict__ bias,
    float* __restrict__ out) {
  __shared__ float v[1024];
  __shared__ float bv[256];
  __shared__ int bi[256];
  int b = blockIdx.x, tid = threadIdx.x;
  for (int i = tid; i < 1024; i += 256) {
    float s = part[(size_t)(0 * 64 + b) * 1024 + i] + part[(size_t)(1 * 64 + b) * 1024 + i] +
              part[(size_t)(2 * 64 + b) * 1024 + i] + part[(size_t)(3 * 64 + b) * 1024 + i];
    v[i] = s + bias[i];
  }
  float* ob = out + (size_t)b * 5 * NTOK;
  for (int i = tid; i < 5 * NTOK; i += 256) ob[i] = 0.f;
  __syncthreads();
  for (int it = 0; it < 5; ++it) {
    float best = -1e38f;
    int bidx = 0x7fffffff;
    for (int i = tid; i < 1024; i += 256) {
      float x = v[i];
      if (x > best || (x == best && i < bidx)) { best = x; bidx = i; }
    }
    bv[tid] = best; bi[tid] = bidx;
    __syncthreads();
    for (int s = 128; s > 0; s >>= 1) {
      if (tid < s) {
        if (bv[tid + s] > bv[tid] || (bv[tid + s] == bv[tid] && bi[tid + s] < bi[tid])) {
          bv[tid] = bv[tid + s]; bi[tid] = bi[tid + s];
        }
      }
      __syncthreads();
    }
    if (tid == 0) {
      ob[it * NTOK + bi[0]] = 1.0f;
      v[bi[0]] = -1e38f;
    }
    __syncthreads();
  }
}

extern "C" void kernel_launch(void* const* d_in, const int* in_sizes, int n_in,
                              void* d_out, int out_size, void* d_ws, size_t ws_size,
                              hipStream_t stream) {
  const float* scene_masks = (const float*)d_in[0];
  const float* target_mask = (const float*)d_in[1];
  const float* emb_W = (const float*)d_in[2];
  const float* emb_b = (const float*)d_in[3];
  const float* class_embed = (const float*)d_in[4];
  const float* scene_pos = (const float*)d_in[5];
  const float* target_pos = (const float*)d_in[6];
  const float* ln1_g = (const float*)d_in[7];
  const float* ln1_b = (const float*)d_in[8];
  const float* ln2_g = (const float*)d_in[9];
  const float* ln2_b = (const float*)d_in[10];
  const float* Wq = (const float*)d_in[11];
  const float* Wk = (const float*)d_in[12];
  const float* Wv = (const float*)d_in[13];
  const float* Wo = (const float*)d_in[14];
  const float* bo = (const float*)d_in[15];
  const float* W1 = (const float*)d_in[16];
  const float* fb1 = (const float*)d_in[17];
  const float* W2 = (const float*)d_in[18];
  const float* fb2 = (const float*)d_in[19];
  const float* mlp_W = (const float*)d_in[20];
  const float* mlp_b = (const float*)d_in[21];
  float* out = (float*)d_out;

  float* ws = (float*)d_ws;
  float* scene = ws;                       // 25190400
  float* Mbuf = scene + 25190400;          // 49152
  float* Wvo = Mbuf + 49152;               // 7077888
  float* tq = Wvo + 7077888;               // 49152
  float* ctxf = tq + 49152;                // 49152
  float* xbuf = ctxf + 49152;              // 49152
  float* xm = xbuf + 49152;                // 49152 (zeroed; rows>=32 stay 0)
  float* partA = xm + 49152;               // 786432
  float* partB = partA + 786432;           // 786432

  // ---- setup ----
  embed_gemm<<<1536, 256, 0, stream>>>(scene_masks, emb_W, emb_b, scene_pos, scene);
  ln_rows<<<32 * NTOK, 256, 0, stream>>>(scene, scene, class_embed, scene_pos);
  tgt_init<<<32, 256, 0, stream>>>(target_mask, emb_W, emb_b, class_embed, target_pos, tq);
  prep_m<<<dim3(16, 12), 256, 0, stream>>>(Wq, Wk, Mbuf);
  prep_wvo<<<dim3(2304, 12), 256, 0, stream>>>(Wv, Wo, Wvo);
  hipMemsetAsync(xm, 0, 49152 * sizeof(float), stream);

  // ---- 12 transformer blocks: 5 launches/layer (LN2 folded into next attn) ----
  for (int l = 0; l < LAYERS; ++l) {
    if (l == 0)
      attn_flash_q<<<32 * NHEADS, 256, 0, stream>>>(
          tq, nullptr, nullptr, nullptr, nullptr, nullptr, 0, nullptr,
          Mbuf, ln1_g, ln1_b, l, scene, ctxf);
    else
      attn_flash_q<<<32 * NHEADS, 256, 0, stream>>>(
          nullptr, partA, fb2 + (l - 1) * 768, ln2_g + (l - 1) * 768,
          ln2_b + (l - 1) * 768, xbuf, 1, tq,
          Mbuf, ln1_g, ln1_b, l, scene, ctxf);
    // out-proj partials: 12 n-tiles x 8 k-chunks(96) -> partA
    skinny_part<<<dim3(12, 8), 256, 0, stream>>>(ctxf, 768, Wvo + (size_t)l * 589824, 96, partA, 768);
    // x = LN1(sum + bo + tq)
    reduce_ln<<<64, 256, 0, stream>>>(partA, 8, bo + l * 768, tq,
                                      ln1_g + l * 768, ln1_b + l * 768, xbuf, nullptr);
    // FF1 partials -> partB
    skinny_part<<<dim3(48, 4), 256, 0, stream>>>(xbuf, 768, W1 + (size_t)l * FF_DIM * 768, 192, partB, FF_DIM);
    // FF2 (inline h1 = relu(sum+b1)) -> partA  [consumed by attn(l+1) or final LN2]
    skinny_h1_part<<<dim3(12, 16), 256, 0, stream>>>(partB, fb1 + l * FF_DIM,
                                                     W2 + (size_t)l * 768 * FF_DIM, 192, partA);
  }
  // final LN2 (l=11): S=16 partials -> tq + xm accumulation
  reduce_ln<<<64, 256, 0, stream>>>(partA, 16, fb2 + 11 * 768, xbuf,
                                    ln2_g + 11 * 768, ln2_b + 11 * 768, tq, xm);

  // ---- head ----
  skinny_part<<<dim3(16, 4), 256, 0, stream>>>(xm, 768, mlp_W, 192, partA, 1024);
  top5_from_parts<<<32, 256, 0, stream>>>(partA, mlp_b, out);
}